// Round 9
// baseline (191.826 us; speedup 1.0000x reference)
//
#include <hip/hip_runtime.h>
#include <math.h>

// Problem constants (match reference)
constexpr int kVerts = 5000;
constexpr int kFaces = 10000;
constexpr int kHalf  = kFaces / 2;
constexpr int kPts   = 16384;   // BATCH * N_PTS = 2 * 8192
constexpr int kOuter = 4;
constexpr int kInner = 50;

#define SCALE 10.0f

// 2-wide fp32 vector -> v_pk_*_f32 (one instruction, two points).
typedef float v2 __attribute__((ext_vector_type(2)));

// ---------------------------------------------------------------------------
// Compile-time Adam bias-correction table (paired rb1/rb2 per step).
// ---------------------------------------------------------------------------
struct BiasTab { float rb[2 * kInner]; };
constexpr BiasTab make_tab() {
    BiasTab t{};
    float b1 = 1.0f, b2 = 1.0f;
    for (int i = 0; i < kInner; ++i) {
        b1 *= 0.9f; b2 *= 0.999f;
        t.rb[2 * i + 0] = 1.0f / (1.0f - b1);
        t.rb[2 * i + 1] = 1.0f / (1.0f - b2);
    }
    return t;
}
__device__ constexpr BiasTab kTab = make_tab();

// ---------------------------------------------------------------------------
// Kernel 0: precompute triangle centers once (bit-identical *_rn formula).
// ---------------------------------------------------------------------------
__global__ __launch_bounds__(256)
void centers_kernel(const float* __restrict__ mesh_V,
                    const int*   __restrict__ mesh_F,
                    float4*      __restrict__ cent)
{
    const int f = blockIdx.x * 256 + threadIdx.x;
    if (f >= kFaces) return;
    const int i0 = mesh_F[f * 3 + 0];
    const int i1 = mesh_F[f * 3 + 1];
    const int i2 = mesh_F[f * 3 + 2];
    const float cx = __fdiv_rn(__fadd_rn(__fadd_rn(mesh_V[i0*3+0], mesh_V[i1*3+0]), mesh_V[i2*3+0]), 3.0f);
    const float cy = __fdiv_rn(__fadd_rn(__fadd_rn(mesh_V[i0*3+1], mesh_V[i1*3+1]), mesh_V[i2*3+1]), 3.0f);
    const float cz = __fdiv_rn(__fadd_rn(__fadd_rn(mesh_V[i0*3+2], mesh_V[i1*3+2]), mesh_V[i2*3+2]), 3.0f);
    const float cc = __fadd_rn(__fadd_rn(__fmul_rn(cx, cx), __fmul_rn(cy, cy)),
                               __fmul_rn(cz, cz));
    cent[f] = make_float4(cx, cy, cz, cc);
}

// ---------------------------------------------------------------------------
// Kernel 1: KNN (K=1), 2 POINTS PER LANE, face-half split, 16 waves/CU.
// R8's 51 us ~= 10k broadcast float4 loads/CU x ~12cyc L1-return. Each load
// now serves 2 points -> 5000 loads/CU (~25 us) vs VALU floor ~23 us.
// grid 256 x 1024: blockIdx = (point-group 0..127 : 128 pts) x (half 0/1).
// Distance tree: frozen bit-exact *_rn sequence (rounds 1-8).
// Tie semantics: even/odd faces go to separate accumulators, each scanned
// ascending with strict < (keeps first); merges are lexicographic (d2,f).
// ---------------------------------------------------------------------------
#define KNN_PARTS 16

__global__ __launch_bounds__(1024)
void knn_kernel(const float* __restrict__ verts,
                const float4* __restrict__ cent,
                float*        __restrict__ ws_d2,   // [2][kPts]
                int*          __restrict__ ws_f)    // [2][kPts]
{
    __shared__ float s_best[KNN_PARTS * 128];
    __shared__ int   s_bestf[KNN_PARTS * 128];

    const int tid  = threadIdx.x;
    const int lane = tid & 63;
    const int part = __builtin_amdgcn_readfirstlane(tid >> 6);   // 0..15
    const int pg   = blockIdx.x >> 1;       // 0..127
    const int half = blockIdx.x & 1;
    const int pA   = pg * 128 + lane;
    const int pB   = pA + 64;

    const float qxA = verts[pA * 3 + 0], qyA = verts[pA * 3 + 1], qzA = verts[pA * 3 + 2];
    const float q2A = __fadd_rn(__fadd_rn(__fmul_rn(qxA, qxA), __fmul_rn(qyA, qyA)),
                                __fmul_rn(qzA, qzA));
    const float qxB = verts[pB * 3 + 0], qyB = verts[pB * 3 + 1], qzB = verts[pB * 3 + 2];
    const float q2B = __fadd_rn(__fadd_rn(__fmul_rn(qxB, qxB), __fmul_rn(qyB, qyB)),
                                __fmul_rn(qzB, qzB));

    const int fbeg = half * kHalf + (part * kHalf) / KNN_PARTS;
    const int fend = half * kHalf + ((part + 1) * kHalf) / KNN_PARTS;

    float bdA0 = INFINITY, bdA1 = INFINITY, bdB0 = INFINITY, bdB1 = INFINITY;
    int   bfA0 = 0x7fffffff, bfA1 = 0x7fffffff, bfB0 = 0x7fffffff, bfB1 = 0x7fffffff;

#define KNN_EVAL(FF, C, QX, QY, QZ, Q2, BD, BF)                                       \
    {                                                                                 \
        const float dot = __fadd_rn(__fadd_rn(__fmul_rn(QX, (C).x),                   \
                                              __fmul_rn(QY, (C).y)),                  \
                                    __fmul_rn(QZ, (C).z));                            \
        const float d2 = __fsub_rn(__fadd_rn(Q2, (C).w), __fmul_rn(2.0f, dot));       \
        if (d2 < (BD)) { (BD) = d2; (BF) = (FF); }                                    \
    }

    int f = fbeg;
#pragma unroll 2
    for (; f + 4 <= fend; f += 4) {
        const float4 c0 = cent[f + 0];   // uniform address -> broadcast, serves 2 pts
        const float4 c1 = cent[f + 1];
        const float4 c2 = cent[f + 2];
        const float4 c3 = cent[f + 3];
        KNN_EVAL(f + 0, c0, qxA, qyA, qzA, q2A, bdA0, bfA0)
        KNN_EVAL(f + 0, c0, qxB, qyB, qzB, q2B, bdB0, bfB0)
        KNN_EVAL(f + 1, c1, qxA, qyA, qzA, q2A, bdA1, bfA1)
        KNN_EVAL(f + 1, c1, qxB, qyB, qzB, q2B, bdB1, bfB1)
        KNN_EVAL(f + 2, c2, qxA, qyA, qzA, q2A, bdA0, bfA0)
        KNN_EVAL(f + 2, c2, qxB, qyB, qzB, q2B, bdB0, bfB0)
        KNN_EVAL(f + 3, c3, qxA, qyA, qzA, q2A, bdA1, bfA1)
        KNN_EVAL(f + 3, c3, qxB, qyB, qzB, q2B, bdB1, bfB1)
    }
    for (; f < fend; ++f) {   // tail faces exceed all batch faces -> acc0 safe
        const float4 c0 = cent[f];
        KNN_EVAL(f, c0, qxA, qyA, qzA, q2A, bdA0, bfA0)
        KNN_EVAL(f, c0, qxB, qyB, qzB, q2B, bdB0, bfB0)
    }
#undef KNN_EVAL

    // lexicographic merge (smaller f wins ties) per point
    if (bdA1 < bdA0 || (bdA1 == bdA0 && bfA1 < bfA0)) { bdA0 = bdA1; bfA0 = bfA1; }
    if (bdB1 < bdB0 || (bdB1 == bdB0 && bfB1 < bfB0)) { bdB0 = bdB1; bfB0 = bfB1; }

    s_best [part * 128 + lane]      = bdA0;  s_bestf[part * 128 + lane]      = bfA0;
    s_best [part * 128 + 64 + lane] = bdB0;  s_bestf[part * 128 + 64 + lane] = bfB0;
    __syncthreads();
    if (part == 0) {
#pragma unroll
        for (int k = 0; k < 2; ++k) {
            const int idx = k * 64 + lane;
            float best  = s_best[idx];
            int   bestf = s_bestf[idx];
            for (int pt = 1; pt < KNN_PARTS; ++pt) {
                const float ob = s_best [pt * 128 + idx];
                const int   of = s_bestf[pt * 128 + idx];
                if (ob < best || (ob == best && of < bestf)) { best = ob; bestf = of; }
            }
            ws_d2[half * kPts + pg * 128 + idx] = best;
            ws_f [half * kPts + pg * 128 + idx] = bestf;
        }
    }
}

// ---------------------------------------------------------------------------
// Kernel 2: solve — TWO INDEPENDENT v2 STREAMS per thread (4 pts/lane).
// R8's v2 (54 us = 648 cyc/iter): packing halved issue (236 cyc) but the two
// packed chains are lockstep -> ~410 cyc of chain stall still exposed.
// A second independent v2 stream fills those stalls: wall/iter ~
// max(2x236, ~410) ~= 520 for 4 points -> ~43 us. Explicit scalars (no
// arrays); per-point expression trees identical to R7/R8.
// 64 blocks x 64 threads; thread t: stream A = pts (t, t+4096),
// stream B = pts (t+8192, t+12288).
// ---------------------------------------------------------------------------
struct SS {
    v2 V0x,V0y,V0z, V1x,V1y,V1z, V2x,V2y,V2z;
    v2 N0x,N0y,N0z, N1x,N1y,N1z, N2x,N2y,N2z;
    v2 E0x,E0y,E0z, E1x,E1y,E1z, F0x,F0y,F0z, F1x,F1y,F1z;
    v2 qx,qy,qz, tx,ty,tz;
    v2 vwu,vwv, du,dv,dd, mAu,mAv,mAd, vAu,vAv,vAd;
};

__device__ __forceinline__ void solve_init(SS& s,
        const float* __restrict__ verts, const float* __restrict__ mesh_V,
        const float* __restrict__ mesh_N, const float* __restrict__ mesh_F_unused,
        const int* __restrict__ mesh_F, int p0, int p1, int fA, int fB)
{
#define LD2(arr, i0, i1) (v2){ arr[i0], arr[i1] }
    const int a0 = mesh_F[fA*3+0], a1 = mesh_F[fA*3+1], a2 = mesh_F[fA*3+2];
    const int b0 = mesh_F[fB*3+0], b1 = mesh_F[fB*3+1], b2 = mesh_F[fB*3+2];
    s.qx = LD2(verts, p0*3+0, p1*3+0);
    s.qy = LD2(verts, p0*3+1, p1*3+1);
    s.qz = LD2(verts, p0*3+2, p1*3+2);
    s.V0x = LD2(mesh_V, a0*3+0, b0*3+0); s.V0y = LD2(mesh_V, a0*3+1, b0*3+1); s.V0z = LD2(mesh_V, a0*3+2, b0*3+2);
    s.V1x = LD2(mesh_V, a1*3+0, b1*3+0); s.V1y = LD2(mesh_V, a1*3+1, b1*3+1); s.V1z = LD2(mesh_V, a1*3+2, b1*3+2);
    s.V2x = LD2(mesh_V, a2*3+0, b2*3+0); s.V2y = LD2(mesh_V, a2*3+1, b2*3+1); s.V2z = LD2(mesh_V, a2*3+2, b2*3+2);
    s.N0x = LD2(mesh_N, a0*3+0, b0*3+0); s.N0y = LD2(mesh_N, a0*3+1, b0*3+1); s.N0z = LD2(mesh_N, a0*3+2, b0*3+2);
    s.N1x = LD2(mesh_N, a1*3+0, b1*3+0); s.N1y = LD2(mesh_N, a1*3+1, b1*3+1); s.N1z = LD2(mesh_N, a1*3+2, b1*3+2);
    s.N2x = LD2(mesh_N, a2*3+0, b2*3+0); s.N2y = LD2(mesh_N, a2*3+1, b2*3+1); s.N2z = LD2(mesh_N, a2*3+2, b2*3+2);
#undef LD2
    s.E0x = s.V0x - s.V2x; s.E0y = s.V0y - s.V2y; s.E0z = s.V0z - s.V2z;
    s.E1x = s.V1x - s.V2x; s.E1y = s.V1y - s.V2y; s.E1z = s.V1z - s.V2z;
    s.F0x = s.N0x - s.N2x; s.F0y = s.N0y - s.N2y; s.F0z = s.N0z - s.N2z;
    s.F1x = s.N1x - s.N2x; s.F1y = s.N1y - s.N2y; s.F1z = s.N1z - s.N2z;
    s.tx = s.qx * SCALE; s.ty = s.qy * SCALE; s.tz = s.qz * SCALE;
    s.vwu = (v2)(1.0f / 3.0f); s.vwv = (v2)(1.0f / 3.0f);
}

__device__ __forceinline__ void outer_reset(SS& s)
{
    const v2 bw0 = (1.0f - s.vwu) - s.vwv;
    const v2 px = ((s.vwu * s.V0x + s.vwv * s.V1x) + bw0 * s.V2x);
    const v2 py = ((s.vwu * s.V0y + s.vwv * s.V1y) + bw0 * s.V2y);
    const v2 pz = ((s.vwu * s.V0z + s.vwv * s.V1z) + bw0 * s.V2z);
    const v2 dx = px - s.qx, dy = py - s.qy, dz = pz - s.qz;
    const v2 dn = (dx * dx + dy * dy) + dz * dz;
    s.dd.x = __builtin_amdgcn_sqrtf(dn.x);
    s.dd.y = __builtin_amdgcn_sqrtf(dn.y);
    s.du = (v2)0.0f; s.dv = (v2)0.0f;
    s.mAu = (v2)0.0f; s.mAv = (v2)0.0f; s.mAd = (v2)0.0f;
    s.vAu = (v2)0.0f; s.vAv = (v2)0.0f; s.vAd = (v2)0.0f;
}

__device__ __forceinline__ void adam_iter(SS& s, float rb1, float rb2)
{
    const float GS = 2.0f / (3.0f * 16384.0f);
    const float B1 = 0.9f,  ONE_M_B1 = 1.0f - 0.9f;
    const float B2 = 0.999f, ONE_M_B2 = 1.0f - 0.999f;

    const v2 bu = s.vwu + s.du;
    const v2 bv = s.vwv + s.dv;
    const v2 bw = (1.0f - bu) - bv;

    const v2 cVx = ((bu * s.V0x + bv * s.V1x) + bw * s.V2x) * SCALE;
    const v2 cVy = ((bu * s.V0y + bv * s.V1y) + bw * s.V2y) * SCALE;
    const v2 cVz = ((bu * s.V0z + bv * s.V1z) + bw * s.V2z) * SCALE;

    const v2 nrx = (bu * s.N0x + bv * s.N1x) + bw * s.N2x;
    const v2 nry = (bu * s.N0y + bv * s.N1y) + bw * s.N2y;
    const v2 nrz = (bu * s.N0z + bv * s.N1z) + bw * s.N2z;
    const v2 nn  = (nrx * nrx + nry * nry) + nrz * nrz;
    v2 inv;
    inv.x = __builtin_amdgcn_rsqf(nn.x);
    inv.y = __builtin_amdgcn_rsqf(nn.y);
    const v2 nhx = nrx * inv, nhy = nry * inv, nhz = nrz * inv;
    const v2 cNx = nhx * SCALE, cNy = nhy * SCALE, cNz = nhz * SCALE;

    const v2 rx = (cVx + cNx * s.dd) - s.tx;
    const v2 ry = (cVy + cNy * s.dd) - s.ty;
    const v2 rz = (cVz + cNz * s.dd) - s.tz;

    const v2 rv0  = (rx * s.E0x + ry * s.E0y) + rz * s.E0z;
    const v2 rv1  = (rx * s.E1x + ry * s.E1y) + rz * s.E1z;
    const v2 rn0  = (rx * s.F0x + ry * s.F0y) + rz * s.F0z;
    const v2 rn1  = (rx * s.F1x + ry * s.F1y) + rz * s.F1z;
    const v2 nf0  = (nhx * s.F0x + nhy * s.F0y) + nhz * s.F0z;
    const v2 nf1  = (nhx * s.F1x + nhy * s.F1y) + nhz * s.F1z;
    const v2 nr_r = (nhx * rx + nhy * ry) + nhz * rz;

    const v2 gu = GS * (SCALE * rv0 + (s.dd * SCALE) * ((rn0 - nr_r * nf0) * inv));
    const v2 gv = GS * (SCALE * rv1 + (s.dd * SCALE) * ((rn1 - nr_r * nf1) * inv));
    const v2 gd = GS * (SCALE * nr_r);

    s.mAu = B1 * s.mAu + ONE_M_B1 * gu;
    s.mAv = B1 * s.mAv + ONE_M_B1 * gv;
    s.mAd = B1 * s.mAd + ONE_M_B1 * gd;
    s.vAu = B2 * s.vAu + ONE_M_B2 * (gu * gu);
    s.vAv = B2 * s.vAv + ONE_M_B2 * (gv * gv);
    s.vAd = B2 * s.vAd + ONE_M_B2 * (gd * gd);

    const v2 au = s.vAu * rb2 + 1e-16f;
    const v2 av = s.vAv * rb2 + 1e-16f;
    const v2 ad = s.vAd * rb2 + 1e-16f;
    v2 su, sv, sd;
    su.x = __builtin_amdgcn_rsqf(au.x);  su.y = __builtin_amdgcn_rsqf(au.y);
    sv.x = __builtin_amdgcn_rsqf(av.x);  sv.y = __builtin_amdgcn_rsqf(av.y);
    sd.x = __builtin_amdgcn_rsqf(ad.x);  sd.y = __builtin_amdgcn_rsqf(ad.y);
    s.du -= 0.01f * (s.mAu * rb1) * su;
    s.dv -= 0.01f * (s.mAv * rb1) * sv;
    s.dd -= 0.01f * (s.mAd * rb1) * sd;
}

__global__ __launch_bounds__(64, 1)
void solve_kernel(const float* __restrict__ verts,
                  const float* __restrict__ mesh_V,
                  const float* __restrict__ mesh_N,
                  const int*   __restrict__ mesh_F,
                  const float* __restrict__ ws_d2,
                  const int*   __restrict__ ws_f,
                  float*       __restrict__ out)
{
    const int t = blockIdx.x * 64 + threadIdx.x;   // 0..4095
    const int pA0 = t, pA1 = t + 4096, pB0 = t + 8192, pB1 = t + 12288;

    // merge halves (half 0 wins ties == first occurrence) + write fidx
    int fsA0, fsA1, fsB0, fsB1;
#define MERGE(P, OUTF)                                                         \
    {                                                                          \
        const float da = ws_d2[(P)];                                           \
        const float db = ws_d2[kPts + (P)];                                    \
        const int   fa = ws_f[(P)];                                            \
        const int   fb = ws_f[kPts + (P)];                                     \
        (OUTF) = (db < da) ? fb : fa;                                          \
        out[(P)] = (float)(OUTF);                                              \
    }
    MERGE(pA0, fsA0) MERGE(pA1, fsA1) MERGE(pB0, fsB0) MERGE(pB1, fsB1)
#undef MERGE

    SS sA, sB;
    solve_init(sA, verts, mesh_V, mesh_N, nullptr, mesh_F, pA0, pA1, fsA0, fsA1);
    solve_init(sB, verts, mesh_V, mesh_N, nullptr, mesh_F, pB0, pB1, fsB0, fsB1);

    for (int outer = 0; outer < kOuter; ++outer) {
        outer_reset(sA);
        outer_reset(sB);
#pragma unroll 2
        for (int it = 0; it < kInner; ++it) {
            const float rb1 = kTab.rb[2 * it + 0];   // uniform s_load, all chains
            const float rb2 = kTab.rb[2 * it + 1];
            adam_iter(sA, rb1, rb2);   // independent streams -> scheduler
            adam_iter(sB, rb1, rb2);   // interleaves to hide chain stalls
        }
        sA.vwu += sA.du;  sA.vwv += sA.dv;
        sB.vwu += sB.du;  sB.vwv += sB.dv;
    }

    out[kPts + 2 * pA0 + 0] = sA.vwu.x;  out[kPts + 2 * pA0 + 1] = sA.vwv.x;
    out[kPts + 2 * pA1 + 0] = sA.vwu.y;  out[kPts + 2 * pA1 + 1] = sA.vwv.y;
    out[kPts + 2 * pB0 + 0] = sB.vwu.x;  out[kPts + 2 * pB0 + 1] = sB.vwv.x;
    out[kPts + 2 * pB1 + 0] = sB.vwu.y;  out[kPts + 2 * pB1 + 1] = sB.vwv.y;
    out[3 * kPts + pA0] = 0.0f;
    out[3 * kPts + pA1] = 0.0f;
    out[3 * kPts + pB0] = 0.0f;
    out[3 * kPts + pB1] = 0.0f;   // outlier_mask = False
}

extern "C" void kernel_launch(void* const* d_in, const int* in_sizes, int n_in,
                              void* d_out, int out_size, void* d_ws, size_t ws_size,
                              hipStream_t stream) {
    const float* verts  = (const float*)d_in[0];
    const float* mesh_V = (const float*)d_in[1];
    const float* mesh_N = (const float*)d_in[2];
    const int*   mesh_F = (const int*)d_in[3];
    float* out = (float*)d_out;

    // workspace: centers | d2 candidates [2][kPts] | face candidates [2][kPts]
    float4* ws_cent = (float4*)d_ws;                                    // 160 KB
    float*  ws_d2   = (float*)((char*)d_ws + kFaces * sizeof(float4));  // 128 KB
    int*    ws_f    = (int*)((char*)ws_d2 + 2 * kPts * sizeof(float));  // 128 KB

    hipLaunchKernelGGL(centers_kernel, dim3((kFaces + 255) / 256), dim3(256), 0, stream,
                       mesh_V, mesh_F, ws_cent);
    hipLaunchKernelGGL(knn_kernel,     dim3(256), dim3(1024), 0, stream,
                       verts, ws_cent, ws_d2, ws_f);
    hipLaunchKernelGGL(solve_kernel,   dim3(4096 / 64), dim3(64), 0, stream,
                       verts, mesh_V, mesh_N, mesh_F, ws_d2, ws_f, out);
}

// Round 10
// 147.617 us; speedup vs baseline: 1.2995x; 1.2995x over previous
//
#include <hip/hip_runtime.h>
#include <math.h>

// Problem constants (match reference)
constexpr int kVerts = 5000;
constexpr int kFaces = 10000;
constexpr int kPts   = 16384;   // BATCH * N_PTS = 2 * 8192
constexpr int kOuter = 4;
constexpr int kInner = 50;

#define SCALE 10.0f

// NOTE: NO __device__ globals in this TU. Rounds 1/2/5 (no device global)
// showed zero graph-residual; rounds 3/4/6-9 (with __device__ kTab) all
// carried a ~47 us per-replay residual. This round tests that hypothesis by
// computing Adam bias corrections in registers instead.

// 2-wide fp32 vector -> v_pk_*_f32 (one instruction, two points).
typedef float v2 __attribute__((ext_vector_type(2)));

// ---------------------------------------------------------------------------
// Kernel 0: precompute triangle centers once (bit-identical *_rn formula).
// ---------------------------------------------------------------------------
__global__ __launch_bounds__(256)
void centers_kernel(const float* __restrict__ mesh_V,
                    const int*   __restrict__ mesh_F,
                    float4*      __restrict__ cent)
{
    const int f = blockIdx.x * 256 + threadIdx.x;
    if (f >= kFaces) return;
    const int i0 = mesh_F[f * 3 + 0];
    const int i1 = mesh_F[f * 3 + 1];
    const int i2 = mesh_F[f * 3 + 2];
    const float cx = __fdiv_rn(__fadd_rn(__fadd_rn(mesh_V[i0*3+0], mesh_V[i1*3+0]), mesh_V[i2*3+0]), 3.0f);
    const float cy = __fdiv_rn(__fadd_rn(__fadd_rn(mesh_V[i0*3+1], mesh_V[i1*3+1]), mesh_V[i2*3+1]), 3.0f);
    const float cz = __fdiv_rn(__fadd_rn(__fadd_rn(mesh_V[i0*3+2], mesh_V[i1*3+2]), mesh_V[i2*3+2]), 3.0f);
    const float cc = __fadd_rn(__fadd_rn(__fmul_rn(cx, cx), __fmul_rn(cy, cy)),
                               __fmul_rn(cz, cz));
    cent[f] = make_float4(cx, cy, cz, cc);
}

// ---------------------------------------------------------------------------
// Kernel 1: KNN (K=1) — Round-7's 4-points/lane version (bounded <54.3 us by
// R7's top-5; est ~46). blockIdx = (point-group 0..63) x (face-quarter 0..3);
// 16 waves/CU; each uniform center load serves 4 points. Candidates to
// ws[4][kPts]; solve merges quarters (strict <, ascending quarter ==
// first-occurrence ties). Distance tree: frozen bit-exact *_rn sequence.
// ---------------------------------------------------------------------------
#define KNN_PARTS 16
#define KNN_SPLIT 4
constexpr int kQLen = kFaces / KNN_SPLIT;   // 2500

__global__ __launch_bounds__(1024)
void knn_kernel(const float* __restrict__ verts,
                const float4* __restrict__ cent,
                float*        __restrict__ ws_d2,   // [4][kPts]
                int*          __restrict__ ws_f)    // [4][kPts]
{
    __shared__ float s_best[KNN_PARTS * 256];
    __shared__ int   s_bestf[KNN_PARTS * 256];

    const int tid  = threadIdx.x;
    const int lane = tid & 63;
    const int part = __builtin_amdgcn_readfirstlane(tid >> 6);   // 0..15
    const int pgi  = blockIdx.x >> 2;       // 0..63
    const int quar = blockIdx.x & 3;        // 0..3
    const int p0   = pgi * 256 + lane;      // 4 points: p0 + 64*k

#define KNN_LOADQ(K)                                                                  \
    const float qx##K = verts[(p0 + 64 * (K)) * 3 + 0];                               \
    const float qy##K = verts[(p0 + 64 * (K)) * 3 + 1];                               \
    const float qz##K = verts[(p0 + 64 * (K)) * 3 + 2];                               \
    const float q2##K = __fadd_rn(__fadd_rn(__fmul_rn(qx##K, qx##K),                  \
                                            __fmul_rn(qy##K, qy##K)),                 \
                                  __fmul_rn(qz##K, qz##K));                           \
    float bd##K = INFINITY; int bf##K = 0x7fffffff;
    KNN_LOADQ(0) KNN_LOADQ(1) KNN_LOADQ(2) KNN_LOADQ(3)
#undef KNN_LOADQ

    const int fbeg = quar * kQLen + (part * kQLen) / KNN_PARTS;
    const int fend = quar * kQLen + ((part + 1) * kQLen) / KNN_PARTS;

#define KNN_EVAL(FF, C, K)                                                            \
    {                                                                                 \
        const float dot = __fadd_rn(__fadd_rn(__fmul_rn(qx##K, (C).x),                \
                                              __fmul_rn(qy##K, (C).y)),               \
                                    __fmul_rn(qz##K, (C).z));                         \
        const float d2 = __fsub_rn(__fadd_rn(q2##K, (C).w), __fmul_rn(2.0f, dot));    \
        if (d2 < bd##K) { bd##K = d2; bf##K = (FF); }                                 \
    }
#define KNN_EVAL4(FF, C) KNN_EVAL(FF, C, 0) KNN_EVAL(FF, C, 1) KNN_EVAL(FF, C, 2) KNN_EVAL(FF, C, 3)

    int f = fbeg;
    for (; f + 4 <= fend; f += 4) {
        const float4 c0 = cent[f + 0];   // uniform address, one load / 4-pt reuse
        const float4 c1 = cent[f + 1];
        const float4 c2 = cent[f + 2];
        const float4 c3 = cent[f + 3];
        KNN_EVAL4(f + 0, c0)
        KNN_EVAL4(f + 1, c1)
        KNN_EVAL4(f + 2, c2)
        KNN_EVAL4(f + 3, c3)
    }
    for (; f < fend; ++f) {
        const float4 c0 = cent[f];
        KNN_EVAL4(f, c0)
    }
#undef KNN_EVAL4
#undef KNN_EVAL

    s_best [part * 256 + 0 * 64 + lane] = bd0;  s_bestf[part * 256 + 0 * 64 + lane] = bf0;
    s_best [part * 256 + 1 * 64 + lane] = bd1;  s_bestf[part * 256 + 1 * 64 + lane] = bf1;
    s_best [part * 256 + 2 * 64 + lane] = bd2;  s_bestf[part * 256 + 2 * 64 + lane] = bf2;
    s_best [part * 256 + 3 * 64 + lane] = bd3;  s_bestf[part * 256 + 3 * 64 + lane] = bf3;
    __syncthreads();
    if (part == 0) {
#pragma unroll
        for (int k = 0; k < 4; ++k) {
            float best  = s_best [k * 64 + lane];
            int   bestf = s_bestf[k * 64 + lane];
            for (int pt = 1; pt < KNN_PARTS; ++pt) {
                const float ob = s_best [pt * 256 + k * 64 + lane];
                const int   of = s_bestf[pt * 256 + k * 64 + lane];
                if (ob < best || (ob == best && of < bestf)) { best = ob; bestf = of; }
            }
            ws_d2[quar * kPts + p0 + 64 * k] = best;
            ws_f [quar * kPts + p0 + 64 * k] = bestf;
        }
    }
}

// ---------------------------------------------------------------------------
// Kernel 2: solve — Round-8's v2-packed kernel (measured 54 us, VGPR 64,
// no scratch), with TWO changes:
//  * bias corrections computed ITERATIVELY IN REGISTERS (b1t*=0.9f;
//    rb=rcp(1-b1t)) instead of a __device__ table -> no device global in
//    the module (residual hypothesis), and the tiny independent scalar
//    chain fills stall slots. <=2 ulp vs table, same class as rsq folds.
//  * merge adapted to 4 face-quarters (strict <, ascending quarter).
// 128 blocks x 64 threads; thread t handles p = t and p = t + 8192.
// ---------------------------------------------------------------------------
__global__ __launch_bounds__(64)
void solve_kernel(const float* __restrict__ verts,
                  const float* __restrict__ mesh_V,
                  const float* __restrict__ mesh_N,
                  const int*   __restrict__ mesh_F,
                  const float* __restrict__ ws_d2,
                  const int*   __restrict__ ws_f,
                  float*       __restrict__ out)
{
    const int t = blockIdx.x * 64 + threadIdx.x;   // 0..8191
    int fsel[2];

#pragma unroll
    for (int k = 0; k < 2; ++k) {
        const int p = t + k * 8192;
        // merge quarters: strict < keeps lowest quarter (= smallest face
        // index) on ties == global first occurrence
        float best = ws_d2[p];
        int   bf   = ws_f[p];
#pragma unroll
        for (int q = 1; q < 4; ++q) {
            const float d  = ws_d2[q * kPts + p];
            const int   ff = ws_f[q * kPts + p];
            if (d < best) { best = d; bf = ff; }
        }
        fsel[k] = bf;
        out[p] = (float)bf;
    }

#define LD2(arr, idx0, idx1) (v2){ arr[idx0], arr[idx1] }
    const int fA = fsel[0], fB = fsel[1];
    const int a0 = mesh_F[fA*3+0], a1 = mesh_F[fA*3+1], a2 = mesh_F[fA*3+2];
    const int b0 = mesh_F[fB*3+0], b1 = mesh_F[fB*3+1], b2 = mesh_F[fB*3+2];

    const v2 qx = LD2(verts, t*3+0, (t+8192)*3+0);
    const v2 qy = LD2(verts, t*3+1, (t+8192)*3+1);
    const v2 qz = LD2(verts, t*3+2, (t+8192)*3+2);

    const v2 V0x = LD2(mesh_V, a0*3+0, b0*3+0), V0y = LD2(mesh_V, a0*3+1, b0*3+1), V0z = LD2(mesh_V, a0*3+2, b0*3+2);
    const v2 V1x = LD2(mesh_V, a1*3+0, b1*3+0), V1y = LD2(mesh_V, a1*3+1, b1*3+1), V1z = LD2(mesh_V, a1*3+2, b1*3+2);
    const v2 V2x = LD2(mesh_V, a2*3+0, b2*3+0), V2y = LD2(mesh_V, a2*3+1, b2*3+1), V2z = LD2(mesh_V, a2*3+2, b2*3+2);
    const v2 N0x = LD2(mesh_N, a0*3+0, b0*3+0), N0y = LD2(mesh_N, a0*3+1, b0*3+1), N0z = LD2(mesh_N, a0*3+2, b0*3+2);
    const v2 N1x = LD2(mesh_N, a1*3+0, b1*3+0), N1y = LD2(mesh_N, a1*3+1, b1*3+1), N1z = LD2(mesh_N, a1*3+2, b1*3+2);
    const v2 N2x = LD2(mesh_N, a2*3+0, b2*3+0), N2y = LD2(mesh_N, a2*3+1, b2*3+1), N2z = LD2(mesh_N, a2*3+2, b2*3+2);
#undef LD2

    const v2 E0x = V0x - V2x, E0y = V0y - V2y, E0z = V0z - V2z;
    const v2 E1x = V1x - V2x, E1y = V1y - V2y, E1z = V1z - V2z;
    const v2 F0x = N0x - N2x, F0y = N0y - N2y, F0z = N0z - N2z;
    const v2 F1x = N1x - N2x, F1y = N1y - N2y, F1z = N1z - N2z;

    const v2 txv = qx * SCALE, tyv = qy * SCALE, tzv = qz * SCALE;
    const float GS = 2.0f / (3.0f * 16384.0f);
    const float B1 = 0.9f,  ONE_M_B1 = 1.0f - 0.9f;
    const float B2 = 0.999f, ONE_M_B2 = 1.0f - 0.999f;

    v2 vwu = (v2)(1.0f / 3.0f), vwv = (v2)(1.0f / 3.0f);

    for (int outer = 0; outer < kOuter; ++outer) {
        const v2 bw0 = (1.0f - vwu) - vwv;
        const v2 px = ((vwu * V0x + vwv * V1x) + bw0 * V2x);
        const v2 py = ((vwu * V0y + vwv * V1y) + bw0 * V2y);
        const v2 pz = ((vwu * V0z + vwv * V1z) + bw0 * V2z);
        const v2 dx = px - qx, dy = py - qy, dz = pz - qz;
        const v2 dn = (dx * dx + dy * dy) + dz * dz;
        v2 dd;
        dd.x = __builtin_amdgcn_sqrtf(dn.x);
        dd.y = __builtin_amdgcn_sqrtf(dn.y);

        v2 du = (v2)0.0f, dv = (v2)0.0f;
        v2 mAu = (v2)0.0f, mAv = (v2)0.0f, mAd = (v2)0.0f;
        v2 vAu = (v2)0.0f, vAv = (v2)0.0f, vAd = (v2)0.0f;
        float b1t = 1.0f, b2t = 1.0f;   // register bias-correction state

#pragma unroll 2
        for (int it = 0; it < kInner; ++it) {
            // independent 6-op scalar chain; fills main-chain stall slots
            b1t *= B1;
            b2t *= B2;
            const float rb1 = __builtin_amdgcn_rcpf(1.0f - b1t);
            const float rb2 = __builtin_amdgcn_rcpf(1.0f - b2t);

            const v2 bu = vwu + du;
            const v2 bv = vwv + dv;
            const v2 bw = (1.0f - bu) - bv;

            const v2 cVx = ((bu * V0x + bv * V1x) + bw * V2x) * SCALE;
            const v2 cVy = ((bu * V0y + bv * V1y) + bw * V2y) * SCALE;
            const v2 cVz = ((bu * V0z + bv * V1z) + bw * V2z) * SCALE;

            const v2 nrx = (bu * N0x + bv * N1x) + bw * N2x;
            const v2 nry = (bu * N0y + bv * N1y) + bw * N2y;
            const v2 nrz = (bu * N0z + bv * N1z) + bw * N2z;
            const v2 nn  = (nrx * nrx + nry * nry) + nrz * nrz;
            v2 inv;
            inv.x = __builtin_amdgcn_rsqf(nn.x);
            inv.y = __builtin_amdgcn_rsqf(nn.y);
            const v2 nhx = nrx * inv, nhy = nry * inv, nhz = nrz * inv;
            const v2 cNx = nhx * SCALE, cNy = nhy * SCALE, cNz = nhz * SCALE;

            const v2 rx = (cVx + cNx * dd) - txv;
            const v2 ry = (cVy + cNy * dd) - tyv;
            const v2 rz = (cVz + cNz * dd) - tzv;

            const v2 rv0  = (rx * E0x + ry * E0y) + rz * E0z;
            const v2 rv1  = (rx * E1x + ry * E1y) + rz * E1z;
            const v2 rn0  = (rx * F0x + ry * F0y) + rz * F0z;
            const v2 rn1  = (rx * F1x + ry * F1y) + rz * F1z;
            const v2 nf0  = (nhx * F0x + nhy * F0y) + nhz * F0z;
            const v2 nf1  = (nhx * F1x + nhy * F1y) + nhz * F1z;
            const v2 nr_r = (nhx * rx + nhy * ry) + nhz * rz;

            const v2 gu = GS * (SCALE * rv0 + (dd * SCALE) * ((rn0 - nr_r * nf0) * inv));
            const v2 gv = GS * (SCALE * rv1 + (dd * SCALE) * ((rn1 - nr_r * nf1) * inv));
            const v2 gd = GS * (SCALE * nr_r);

            mAu = B1 * mAu + ONE_M_B1 * gu;
            mAv = B1 * mAv + ONE_M_B1 * gv;
            mAd = B1 * mAd + ONE_M_B1 * gd;
            vAu = B2 * vAu + ONE_M_B2 * (gu * gu);
            vAv = B2 * vAv + ONE_M_B2 * (gv * gv);
            vAd = B2 * vAd + ONE_M_B2 * (gd * gd);

            const v2 au = vAu * rb2 + 1e-16f;
            const v2 av = vAv * rb2 + 1e-16f;
            const v2 ad = vAd * rb2 + 1e-16f;
            v2 su, sv, sd;
            su.x = __builtin_amdgcn_rsqf(au.x);  su.y = __builtin_amdgcn_rsqf(au.y);
            sv.x = __builtin_amdgcn_rsqf(av.x);  sv.y = __builtin_amdgcn_rsqf(av.y);
            sd.x = __builtin_amdgcn_rsqf(ad.x);  sd.y = __builtin_amdgcn_rsqf(ad.y);
            du -= 0.01f * (mAu * rb1) * su;
            dv -= 0.01f * (mAv * rb1) * sv;
            dd -= 0.01f * (mAd * rb1) * sd;
        }
        vwu += du;
        vwv += dv;
    }

#pragma unroll
    for (int k = 0; k < 2; ++k) {
        const int p = t + k * 8192;
        const float u = (k == 0) ? vwu.x : vwu.y;
        const float v = (k == 0) ? vwv.x : vwv.y;
        out[kPts + 2 * p + 0] = u;
        out[kPts + 2 * p + 1] = v;
        out[3 * kPts + p]     = 0.0f;   // outlier_mask = False
    }
}

extern "C" void kernel_launch(void* const* d_in, const int* in_sizes, int n_in,
                              void* d_out, int out_size, void* d_ws, size_t ws_size,
                              hipStream_t stream) {
    const float* verts  = (const float*)d_in[0];
    const float* mesh_V = (const float*)d_in[1];
    const float* mesh_N = (const float*)d_in[2];
    const int*   mesh_F = (const int*)d_in[3];
    float* out = (float*)d_out;

    // workspace: centers | d2 candidates [4][kPts] | face candidates [4][kPts]
    float4* ws_cent = (float4*)d_ws;                                    // 160 KB
    float*  ws_d2   = (float*)((char*)d_ws + kFaces * sizeof(float4));  // 256 KB
    int*    ws_f    = (int*)((char*)ws_d2 + 4 * kPts * sizeof(float));  // 256 KB

    hipLaunchKernelGGL(centers_kernel, dim3((kFaces + 255) / 256), dim3(256), 0, stream,
                       mesh_V, mesh_F, ws_cent);
    hipLaunchKernelGGL(knn_kernel,     dim3((kPts / 256) * KNN_SPLIT), dim3(1024), 0, stream,
                       verts, ws_cent, ws_d2, ws_f);
    hipLaunchKernelGGL(solve_kernel,   dim3(8192 / 64), dim3(64), 0, stream,
                       verts, mesh_V, mesh_N, mesh_F, ws_d2, ws_f, out);
}